// Round 3
// baseline (837.199 us; speedup 1.0000x reference)
//
#include <hip/hip_runtime.h>
#include <hip/hip_bf16.h>
#include <math.h>

#define NN 262144
#define EE 2097152
#define NPER 32768

typedef float4 f4;

// ---------------- degree count (in-deg via dst for CSR+dis, out-deg via src for deg_a)
__global__ __launch_bounds__(256) void k_degree(const int* __restrict__ ei,
                                                int* __restrict__ cnt, int* __restrict__ dega) {
  int stride = gridDim.x * blockDim.x;
  for (int e = blockIdx.x * blockDim.x + threadIdx.x; e < EE; e += stride) {
    int s = ei[e];
    int d = ei[EE + e];
    atomicAdd(&cnt[d], 1);
    atomicAdd(&dega[s], 1);
  }
}

// ---------------- exclusive scan of cnt over N (3 kernels)
__global__ __launch_bounds__(256) void k_scanA(const int* __restrict__ cnt, int* __restrict__ bsum) {
  __shared__ int sm[256];
  int t = threadIdx.x;
  int base = blockIdx.x * 1024 + t * 4;
  int s = cnt[base] + cnt[base + 1] + cnt[base + 2] + cnt[base + 3];
  sm[t] = s;
  __syncthreads();
  for (int off = 128; off > 0; off >>= 1) {
    if (t < off) sm[t] += sm[t + off];
    __syncthreads();
  }
  if (t == 0) bsum[blockIdx.x] = sm[0];
}

__global__ __launch_bounds__(256) void k_scanB(const int* __restrict__ bsum, int* __restrict__ bscan) {
  __shared__ int sm[256];
  int t = threadIdx.x;
  int orig = bsum[t];
  sm[t] = orig;
  __syncthreads();
  for (int off = 1; off < 256; off <<= 1) {
    int v = (t >= off) ? sm[t - off] : 0;
    __syncthreads();
    sm[t] += v;
    __syncthreads();
  }
  bscan[t] = sm[t] - orig;  // exclusive
}

__global__ __launch_bounds__(256) void k_scanC(const int* __restrict__ cnt, const int* __restrict__ bscan,
                                               int* __restrict__ offs, int* __restrict__ cur,
                                               float* __restrict__ dis) {
  __shared__ int sm[256];
  int t = threadIdx.x;
  int base = blockIdx.x * 1024 + t * 4;
  int c0 = cnt[base], c1 = cnt[base + 1], c2 = cnt[base + 2], c3 = cnt[base + 3];
  int s = c0 + c1 + c2 + c3;
  sm[t] = s;
  __syncthreads();
  for (int off = 1; off < 256; off <<= 1) {
    int v = (t >= off) ? sm[t - off] : 0;
    __syncthreads();
    sm[t] += v;
    __syncthreads();
  }
  int ex = sm[t] - s + bscan[blockIdx.x];
  int o0 = ex, o1 = ex + c0, o2 = o1 + c1, o3 = o2 + c2;
  offs[base] = o0; offs[base + 1] = o1; offs[base + 2] = o2; offs[base + 3] = o3;
  cur[base] = o0;  cur[base + 1] = o1;  cur[base + 2] = o2;  cur[base + 3] = o3;
  dis[base]     = rsqrtf((float)(c0 + 1));   // +1 = self loop
  dis[base + 1] = rsqrtf((float)(c1 + 1));
  dis[base + 2] = rsqrtf((float)(c2 + 1));
  dis[base + 3] = rsqrtf((float)(c3 + 1));
}

// ---------------- CSR fill + layer-1 class-weight accumulation (8-class trick)
__global__ __launch_bounds__(256) void k_fill(const int* __restrict__ ei, const int* __restrict__ x,
                                              const float* __restrict__ dis, float* __restrict__ w8,
                                              int* __restrict__ cur, int* __restrict__ adj) {
  int stride = gridDim.x * blockDim.x;
  for (int e = blockIdx.x * blockDim.x + threadIdx.x; e < EE; e += stride) {
    int s = ei[e];
    int d = ei[EE + e];
    float nrm = dis[s] * dis[d];
    int c = x[s];
    atomicAdd(&w8[(size_t)d * 8 + c], nrm);
    int pos = atomicAdd(&cur[d], 1);
    adj[pos] = s;
  }
}

// ---------------- fold self-loop into w8: w8[n][x[n]] += dis[n]^2
__global__ __launch_bounds__(256) void k_self(const int* __restrict__ x, const float* __restrict__ dis,
                                              float* __restrict__ w8) {
  int n = blockIdx.x * 256 + threadIdx.x;
  float dn = dis[n];
  w8[(size_t)n * 8 + x[n]] += dn * dn;
}

// ---------------- M1 = emb_w @ W2  (8x64)
__global__ void k_m1(const float* __restrict__ emb, const float* __restrict__ W2, float* __restrict__ M1) {
  int t = threadIdx.x;  // 512 threads
  int c = t >> 6, j = t & 63;
  float acc = 0.f;
  for (int k = 0; k < 64; ++k) acc += emb[c * 64 + k] * W2[k * 64 + j];
  M1[c * 64 + j] = acc;
}

// relu( w(8) . M1cols(8x4) + b(4) )  -> 4 cols of out1
__device__ inline f4 relu4(const f4 w0, const f4 w1, const f4* mcol, const f4 b) {
  float wv[8] = {w0.x, w0.y, w0.z, w0.w, w1.x, w1.y, w1.z, w1.w};
  float o0 = b.x, o1 = b.y, o2 = b.z, o3 = b.w;
#pragma unroll
  for (int c = 0; c < 8; ++c) {
    o0 += wv[c] * mcol[c].x; o1 += wv[c] * mcol[c].y;
    o2 += wv[c] * mcol[c].z; o3 += wv[c] * mcol[c].w;
  }
  f4 r;
  r.x = fmaxf(o0, 0.f); r.y = fmaxf(o1, 0.f); r.z = fmaxf(o2, 0.f); r.w = fmaxf(o3, 0.f);
  return r;
}

// ---------------- layer 2: CSR gather with on-the-fly out1 recompute (w8 -> relu)
// then @W3+b3,relu + @W1+b1 + softmax -> d_out
__global__ __launch_bounds__(256) void k_layer2(const int* __restrict__ adj, const int* __restrict__ offs,
                                                const int* __restrict__ cnt, const float* __restrict__ dis,
                                                const float* __restrict__ w8, const float* __restrict__ M1,
                                                const float* __restrict__ b2,
                                                const float* __restrict__ W3, const float* __restrict__ b3,
                                                const float* __restrict__ W1, const float* __restrict__ b1,
                                                float* __restrict__ dout) {
  __shared__ float M1l[512];
  __shared__ float aggl[16 * 68];
  __shared__ float o2l[16 * 68];
  int tid = threadIdx.x;
  M1l[tid] = M1[tid];
  M1l[256 + tid] = M1[256 + tid];
  __syncthreads();

  int lane = tid & 63;
  int sub = lane >> 4, part = lane & 15;
  int ndl = ((tid >> 6) << 2) + sub;            // 0..15 node-local
  int node = blockIdx.x * 16 + ndl;
  int j0 = part * 4;

  f4 mcol[8];
#pragma unroll
  for (int c = 0; c < 8; ++c) mcol[c] = *(const f4*)&M1l[c * 64 + j0];
  f4 bb2 = *(const f4*)&b2[j0];

  // phase 1: aggregate over in-edges (16 lanes x f32x4 per node), out1 recomputed from w8
  float dn = dis[node];
  float d2 = dn * dn;
  int off = offs[node];
  int c = cnt[node];
  const f4* wrow = (const f4*)&w8[(size_t)node * 8];
  f4 v = relu4(wrow[0], wrow[1], mcol, bb2);
  float ax = d2 * v.x, ay = d2 * v.y, az = d2 * v.z, aw = d2 * v.w;  // self loop
  for (int it = 0; it < c; ++it) {
    int s = adj[off + it];
    const f4* wr = (const f4*)&w8[(size_t)s * 8];
    f4 u0 = wr[0], u1 = wr[1];
    float nrm = dis[s] * dn;
    f4 m = relu4(u0, u1, mcol, bb2);
    ax += nrm * m.x; ay += nrm * m.y; az += nrm * m.z; aw += nrm * m.w;
  }
  f4 st; st.x = ax; st.y = ay; st.z = az; st.w = aw;
  *(f4*)&aggl[ndl * 68 + j0] = st;
  __syncthreads();

  // phase 3a: o2 = relu(agg @ W3 + b3). thread owns column j for 4 nodes (W3 reg reuse x4)
  {
    int w = tid >> 6;       // node group 0..3
    int j = tid & 63;
    float bb = b3[j];
    float o0 = bb, o1 = bb, o2 = bb, o3 = bb;
    for (int k = 0; k < 64; ++k) {
      float wk = W3[k * 64 + j];
      o0 += aggl[(w * 4 + 0) * 68 + k] * wk;
      o1 += aggl[(w * 4 + 1) * 68 + k] * wk;
      o2 += aggl[(w * 4 + 2) * 68 + k] * wk;
      o3 += aggl[(w * 4 + 3) * 68 + k] * wk;
    }
    o2l[(w * 4 + 0) * 68 + j] = fmaxf(o0, 0.f);
    o2l[(w * 4 + 1) * 68 + j] = fmaxf(o1, 0.f);
    o2l[(w * 4 + 2) * 68 + j] = fmaxf(o2, 0.f);
    o2l[(w * 4 + 3) * 68 + j] = fmaxf(o3, 0.f);
  }
  __syncthreads();

  // phase 3b: s = o2 @ W1 + b1, softmax over 16 lanes
  int nd2 = tid >> 4, t16 = tid & 15;
  float sv = b1[t16];
  const float* o2p = &o2l[nd2 * 68];
  for (int j = 0; j < 64; ++j) sv += o2p[j] * W1[j * 16 + t16];
  float mx = sv;
#pragma unroll
  for (int m = 1; m < 16; m <<= 1) mx = fmaxf(mx, __shfl_xor(mx, m));
  float ex = expf(sv - mx);
  float sm = ex;
#pragma unroll
  for (int m = 1; m < 16; m <<= 1) sm += __shfl_xor(sm, m);
  dout[8 + (size_t)blockIdx.x * 256 + tid] = ex / sm;  // == s_b[node][t16], coalesced
}

// ---------------- mincut numerator: sum over edges of dot(s[src], s[dst]) per graph
__global__ __launch_bounds__(256) void k_num(const int* __restrict__ ei, const float* __restrict__ sb,
                                             float* __restrict__ num) {
  __shared__ float red[256];
  int t = threadIdx.x;
  int b = blockIdx.x;
  int g = b >> 7;          // 128 blocks of 2048 edges per graph
  float local = 0.f;
  int base = b * 2048;
#pragma unroll
  for (int r = 0; r < 8; ++r) {
    int e = base + r * 256 + t;
    int s = ei[e];
    int d = ei[EE + e];
    const f4* ps = (const f4*)&sb[(size_t)s * 16];
    const f4* pd = (const f4*)&sb[(size_t)d * 16];
    float dot = 0.f;
#pragma unroll
    for (int q = 0; q < 4; ++q) {
      f4 a = ps[q], c4 = pd[q];
      dot += a.x * c4.x + a.y * c4.y + a.z * c4.z + a.w * c4.w;
    }
    local += dot;
  }
  red[t] = local;
  __syncthreads();
  for (int off = 128; off > 0; off >>= 1) {
    if (t < off) red[t] += red[t + off];
    __syncthreads();
  }
  if (t == 0) atomicAdd(&num[g], red[0]);
}

// ---------------- den + xp + SS per graph (block = 1024 contiguous nodes, one graph)
__global__ __launch_bounds__(256) void k_ssden(const float* __restrict__ sb, const int* __restrict__ dega,
                                               float* __restrict__ den, float* __restrict__ xp,
                                               float* __restrict__ SSb) {
  __shared__ float sl[256 * 17];
  __shared__ float red[256];
  __shared__ float xpl[16];
  int t = threadIdx.x;
  int b = blockIdx.x;
  int g = b >> 5;          // 32 blocks per graph
  int t1 = t >> 4, t2 = t & 15;
  if (t < 16) xpl[t] = 0.f;
  float ss = 0.f;
  float denloc = 0.f;
  float x0 = 0, x1 = 0, x2 = 0, x3 = 0, x4 = 0, x5 = 0, x6 = 0, x7 = 0;
  float x8 = 0, x9 = 0, xA = 0, xB = 0, xC = 0, xD = 0, xE = 0, xF = 0;
  for (int ch = 0; ch < 4; ++ch) {
    int node = b * 1024 + ch * 256 + t;
    const f4* pr = (const f4*)&sb[(size_t)node * 16];
    f4 r0 = pr[0], r1 = pr[1], r2 = pr[2], r3 = pr[3];
    float q = r0.x * r0.x + r0.y * r0.y + r0.z * r0.z + r0.w * r0.w
            + r1.x * r1.x + r1.y * r1.y + r1.z * r1.z + r1.w * r1.w
            + r2.x * r2.x + r2.y * r2.y + r2.z * r2.z + r2.w * r2.w
            + r3.x * r3.x + r3.y * r3.y + r3.z * r3.z + r3.w * r3.w;
    denloc += q * (float)dega[node];
    x0 += r0.x; x1 += r0.y; x2 += r0.z; x3 += r0.w;
    x4 += r1.x; x5 += r1.y; x6 += r1.z; x7 += r1.w;
    x8 += r2.x; x9 += r2.y; xA += r2.z; xB += r2.w;
    xC += r3.x; xD += r3.y; xE += r3.z; xF += r3.w;
    float* row = &sl[t * 17];
    row[0] = r0.x; row[1] = r0.y; row[2] = r0.z; row[3] = r0.w;
    row[4] = r1.x; row[5] = r1.y; row[6] = r1.z; row[7] = r1.w;
    row[8] = r2.x; row[9] = r2.y; row[10] = r2.z; row[11] = r2.w;
    row[12] = r3.x; row[13] = r3.y; row[14] = r3.z; row[15] = r3.w;
    __syncthreads();
    for (int n = 0; n < 256; ++n) ss += sl[n * 17 + t1] * sl[n * 17 + t2];
    __syncthreads();
  }
  atomicAdd(&SSb[g * 256 + t], ss);
  red[t] = denloc;
  __syncthreads();
  for (int off = 128; off > 0; off >>= 1) {
    if (t < off) red[t] += red[t + off];
    __syncthreads();
  }
  if (t == 0) atomicAdd(&den[g], red[0]);
  atomicAdd(&xpl[0], x0);  atomicAdd(&xpl[1], x1);  atomicAdd(&xpl[2], x2);  atomicAdd(&xpl[3], x3);
  atomicAdd(&xpl[4], x4);  atomicAdd(&xpl[5], x5);  atomicAdd(&xpl[6], x6);  atomicAdd(&xpl[7], x7);
  atomicAdd(&xpl[8], x8);  atomicAdd(&xpl[9], x9);  atomicAdd(&xpl[10], xA); atomicAdd(&xpl[11], xB);
  atomicAdd(&xpl[12], xC); atomicAdd(&xpl[13], xD); atomicAdd(&xpl[14], xE); atomicAdd(&xpl[15], xF);
  __syncthreads();
  if (t < 16) atomicAdd(&xp[g * 16 + t], xpl[t]);
}

// ---------------- scalars: mc1, o1, pred
__global__ __launch_bounds__(256) void k_final(const float* __restrict__ accum, const float* __restrict__ ncells,
                                               const float* __restrict__ Wp, const float* __restrict__ bp,
                                               float* __restrict__ dout) {
  __shared__ float red[256];
  __shared__ float bc;
  int t = threadIdx.x;
  const float* num = accum;
  const float* den = accum + 8;
  const float* xp  = accum + 16;
  const float* SSb = accum + 144;
  float o1s = 0.f;
  for (int g = 0; g < 8; ++g) {
    float v = SSb[g * 256 + t];
    red[t] = v * v;
    __syncthreads();
    for (int off = 128; off > 0; off >>= 1) {
      if (t < off) red[t] += red[t + off];
      __syncthreads();
    }
    if (t == 0) bc = sqrtf(red[0]);
    __syncthreads();
    float nrm = bc;
    float diag = ((t >> 4) == (t & 15)) ? 0.25f : 0.f;  // I/sqrt(16)
    float dv = v / nrm - diag;
    red[t] = dv * dv;
    __syncthreads();
    for (int off = 128; off > 0; off >>= 1) {
      if (t < off) red[t] += red[t + off];
      __syncthreads();
    }
    if (t == 0) o1s += sqrtf(red[0]);
    __syncthreads();
  }
  if (t == 0) {
    dout[8 + (size_t)NN * 16 + 1] = o1s / 8.f;
    float m = 0.f;
    for (int g = 0; g < 8; ++g) m += -num[g] / den[g];
    dout[8 + (size_t)NN * 16] = m / 8.f;
  }
  if (t < 8) {
    float p = bp[0];
    for (int k = 0; k < 16; ++k) p += (xp[t * 16 + k] / ncells[t]) * Wp[k];
    dout[t] = p;
  }
}

extern "C" void kernel_launch(void* const* d_in, const int* in_sizes, int n_in,
                              void* d_out, int out_size, void* d_ws, size_t ws_size,
                              hipStream_t stream) {
  const int* x            = (const int*)d_in[0];
  const int* ei           = (const int*)d_in[1];   // int32! (JAX x64 disabled)
  // d_in[2] = batch (derivable: node / 32768) — unused
  const float* ncells     = (const float*)d_in[3];
  const float* emb        = (const float*)d_in[4];
  const float* W2         = (const float*)d_in[5];
  const float* b2         = (const float*)d_in[6];
  const float* W3         = (const float*)d_in[7];
  const float* b3         = (const float*)d_in[8];
  const float* W1         = (const float*)d_in[9];
  const float* b1         = (const float*)d_in[10];
  const float* Wp         = (const float*)d_in[11];
  const float* bp         = (const float*)d_in[12];
  float* dout = (float*)d_out;

  // workspace layout (~22 MB)
  char* w = (char*)d_ws;
  int* cnt     = (int*)w;                              // N
  int* dega    = cnt + NN;                             // N
  float* w8    = (float*)(dega + NN);                  // 8N
  float* accum = w8 + (size_t)8 * NN;                  // 2192 floats: num8, den8, xp128, SS2048
  float* num   = accum;
  float* den   = accum + 8;
  float* xp    = accum + 16;
  float* SSb   = accum + 144;
  float* dis   = accum + 2192;                         // N
  int* offs    = (int*)(dis + NN);                     // N
  int* cur     = offs + NN;                            // N
  int* adj     = cur + NN;                             // E
  int* bsum    = adj + EE;                             // 256
  int* bscan   = bsum + 256;                           // 256
  float* M1    = (float*)(bscan + 256);                // 512

  size_t zbytes = (size_t)(10 * NN) * 4 + 2192 * 4;    // cnt, dega, w8, accum
  hipMemsetAsync(d_ws, 0, zbytes, stream);

  k_degree<<<2048, 256, 0, stream>>>(ei, cnt, dega);
  k_scanA <<<256, 256, 0, stream>>>(cnt, bsum);
  k_scanB <<<1, 256, 0, stream>>>(bsum, bscan);
  k_scanC <<<256, 256, 0, stream>>>(cnt, bscan, offs, cur, dis);
  k_fill  <<<2048, 256, 0, stream>>>(ei, x, dis, w8, cur, adj);
  k_self  <<<1024, 256, 0, stream>>>(x, dis, w8);
  k_m1    <<<1, 512, 0, stream>>>(emb, W2, M1);
  k_layer2<<<16384, 256, 0, stream>>>(adj, offs, cnt, dis, w8, M1, b2, W3, b3, W1, b1, dout);
  k_num   <<<1024, 256, 0, stream>>>(ei, dout + 8, num);
  k_ssden <<<256, 256, 0, stream>>>(dout + 8, dega, den, xp, SSb);
  k_final <<<1, 256, 0, stream>>>(accum, ncells, Wp, bp, dout);
}